// Round 9
// baseline (558.890 us; speedup 1.0000x reference)
//
#include <hip/hip_runtime.h>

#define BN_EPS 1e-5f

__device__ __forceinline__ float lrelu(float x){ return x > 0.f ? x : 0.2f*x; }

struct F3 { float x, y, z; };   // 12B -> global_load_dwordx3

#define EB 4096          // edges per partition block

// ---------------- merged histograms: node degree + bucket counts --------------
__global__ __launch_bounds__(256) void hist2_k(const int* __restrict__ dst,
                                               int* __restrict__ deg,
                                               int* __restrict__ bcnt, int E){
  __shared__ int bh[512];
  int t = threadIdx.x;
  bh[t] = 0; bh[t+256] = 0;
  __syncthreads();
  int e0 = blockIdx.x*EB;
  for (int i = 0; i < EB/256; ++i){
    int e = e0 + i*256 + t;
    if (e < E){
      int d = dst[e];
      atomicAdd(&deg[d], 1);
      atomicAdd(&bh[d >> 7], 1);
    }
  }
  __syncthreads();
  if (bh[t])     atomicAdd(&bcnt[t],     bh[t]);
  if (bh[t+256]) atomicAdd(&bcnt[t+256], bh[t+256]);
}

// ---------------- CSR offset scan ----------------
__global__ __launch_bounds__(256) void scan1_k(int* __restrict__ degoff,
                                               int* __restrict__ bsum, int N){
  __shared__ int s[256];
  int t = threadIdx.x, i = blockIdx.x*256 + t;
  int v = (i < N) ? degoff[i] : 0;
  s[t] = v; __syncthreads();
  int x = v;
  for (int d = 1; d < 256; d <<= 1){
    int y = (t >= d) ? s[t-d] : 0;
    __syncthreads();
    x += y; s[t] = x;
    __syncthreads();
  }
  if (i < N) degoff[i] = x - v;
  if (t == 255) bsum[blockIdx.x] = x;
}

__global__ __launch_bounds__(256) void scan2_k(int* __restrict__ bsum, int nb){
  __shared__ int s[256];
  int t = threadIdx.x;
  int v = (t < nb) ? bsum[t] : 0;
  s[t] = v; __syncthreads();
  int x = v;
  for (int d = 1; d < 256; d <<= 1){
    int y = (t >= d) ? s[t-d] : 0;
    __syncthreads();
    x += y; s[t] = x;
    __syncthreads();
  }
  if (t < nb) bsum[t] = x - v;
}

__global__ __launch_bounds__(256) void scan3_k(int* __restrict__ off,
                                               const int* __restrict__ bsum,
                                               int N, int E){
  int i = blockIdx.x*256 + threadIdx.x;
  if (i < N) off[i] += bsum[blockIdx.x];
  if (i == 0) off[N] = E;
}

// ---------------- bucketed edge partition ----------------
__global__ __launch_bounds__(512) void bscan_k(const int* __restrict__ bcnt,
                                               int* __restrict__ bkt_off,
                                               int* __restrict__ gcur, int E){
  __shared__ int s[512];
  int t = threadIdx.x;
  int v = bcnt[t];
  s[t] = v; __syncthreads();
  int x = v;
  for (int d = 1; d < 512; d <<= 1){
    int y = (t >= d) ? s[t-d] : 0;
    __syncthreads();
    x += y; s[t] = x;
    __syncthreads();
  }
  bkt_off[t] = x - v;
  gcur[t]    = x - v;
  if (t == 511) bkt_off[512] = E;
}

__global__ __launch_bounds__(256) void bpart_k(const int* __restrict__ src,
                                               const int* __restrict__ dst,
                                               int* __restrict__ gcur,
                                               int2* __restrict__ ebuf, int E){
  __shared__ int bh[512];
  __shared__ int base[512];
  int t = threadIdx.x;
  bh[t] = 0; bh[t+256] = 0;
  __syncthreads();
  int e0 = blockIdx.x*EB;
  for (int i = 0; i < EB/256; ++i){
    int e = e0 + i*256 + t;
    if (e < E) atomicAdd(&bh[dst[e] >> 7], 1);
  }
  __syncthreads();
  #pragma unroll
  for (int h = 0; h < 2; ++h){
    int b = t + h*256;
    base[b] = bh[b] ? atomicAdd(&gcur[b], bh[b]) : 0;
  }
  __syncthreads();
  for (int i = 0; i < EB/256; ++i){
    int e = e0 + i*256 + t;
    if (e < E){
      int s = src[e], d = dst[e];
      int p = atomicAdd(&base[d >> 7], 1);
      ebuf[p] = make_int2(s, d);
    }
  }
}

__global__ __launch_bounds__(256) void bscat_k(const int2* __restrict__ ebuf,
                                               const int* __restrict__ bkt_off,
                                               const int* __restrict__ off,
                                               int* __restrict__ srcs, int N){
  __shared__ int lcur[128];
  int b = blockIdx.x, t = threadIdx.x;
  int node_lo = b << 7;
  if (t < 128){
    int n = node_lo + t;
    lcur[t] = (n < N) ? off[n] : 0;
  }
  __syncthreads();
  int eb = bkt_off[b], ee = bkt_off[b+1];
  for (int e = eb + t; e < ee; e += 256){
    int2 sd = ebuf[e];
    int p = atomicAdd(&lcur[sd.y - node_lo], 1);
    srcs[p] = sd.x;
  }
}

// ---------------- GIN aggregation: lane owns feats 3ln..3ln+2 -----------------
__global__ __launch_bounds__(256) void agg_k(const float* __restrict__ hin,
                                             float* __restrict__ hout,
                                             const int* __restrict__ off,
                                             const int* __restrict__ srcs, int N){
  int node = blockIdx.x*8 + (threadIdx.x >> 5);
  int ln = threadIdx.x & 31;
  if (node >= N) return;
  F3 a = *((const F3*)(hin + (size_t)node*96) + ln);
  float bx = 0.f, by = 0.f, bz = 0.f;
  int jb = off[node], je = off[node+1];
  int j = jb;
  for (; j+1 < je; j += 2){
    int s0 = srcs[j], s1 = srcs[j+1];
    F3 q0 = *((const F3*)(hin + (size_t)s0*96) + ln);
    F3 q1 = *((const F3*)(hin + (size_t)s1*96) + ln);
    a.x += q0.x; a.y += q0.y; a.z += q0.z;
    bx  += q1.x; by  += q1.y; bz  += q1.z;
  }
  if (j < je){
    int s0 = srcs[j];
    F3 q0 = *((const F3*)(hin + (size_t)s0*96) + ln);
    a.x += q0.x; a.y += q0.y; a.z += q0.z;
  }
  a.x += bx; a.y += by; a.z += bz;
  *((F3*)(hout + (size_t)node*96) + ln) = a;
}

// ---------------- fused MLP: 4-node x 12-dim register micro-tile --------------
// 128 thr / 2 waves; 64-node tile. Thread (dg=t&7, np=t>>3) owns dims
// d0=dg*12, nodes n0=np*4. Per k: 1 float4 hT read + 3 b128 W reads (all LDS,
// in-order lgkm, broadcast-friendly) + 48 FMA -> 12:1 FMA:DS.
// W1/W2 staged in LDS (reloaded between GEMMs). LDS 63KB -> 2 blocks/CU.
__global__ __launch_bounds__(128) void mlp_mt_k(
    const float* __restrict__ hin, float* __restrict__ hout,
    const float* __restrict__ W1, const float* __restrict__ b1,
    const float* __restrict__ g, const float* __restrict__ beta,
    const float* __restrict__ mean, const float* __restrict__ var,
    const float* __restrict__ W2, const float* __restrict__ b2, int N)
{
  __shared__ float Ws[96*96];          // 36.9 KB
  __shared__ float hT[96*68];          // 26.1 KB, [k][n] pad 68 (16B-aligned rows)
  int t = threadIdx.x;
  int nbase = blockIdx.x * 64;
  int lim = (N - nbase) * 96;
  const float* hbase = hin + (size_t)nbase*96;

  #pragma unroll
  for (int i = 0; i < 18; ++i)         // stage W1 (9216 dwords / 128 thr)
    ((float4*)Ws)[t + 128*i] = ((const float4*)W1)[t + 128*i];
  #pragma unroll
  for (int i = 0; i < 48; ++i){        // stage h transposed
    int e = t + 128*i;
    float v = (e < lim) ? hbase[e] : 0.f;
    int n = e / 96, k = e - n*96;
    hT[k*68 + n] = v;
  }
  __syncthreads();

  int dg = t & 7, np = t >> 3;
  int d0 = dg*12, n0 = np*4;

  float acc[48];                       // [j][i] = dim j, node i
  #pragma unroll
  for (int j = 0; j < 12; ++j){
    float bj = b1[d0+j];
    #pragma unroll
    for (int i = 0; i < 4; ++i) acc[j*4+i] = bj;
  }
  #pragma unroll 2
  for (int k = 0; k < 96; ++k){
    float4 hv = *(const float4*)&hT[k*68 + n0];
    const float* wr = &Ws[k*96 + d0];
    float w[12];
    *(float4*)&w[0] = *(const float4*)(wr);
    *(float4*)&w[4] = *(const float4*)(wr+4);
    *(float4*)&w[8] = *(const float4*)(wr+8);
    #pragma unroll
    for (int j = 0; j < 12; ++j){
      acc[j*4+0] = fmaf(hv.x, w[j], acc[j*4+0]);
      acc[j*4+1] = fmaf(hv.y, w[j], acc[j*4+1]);
      acc[j*4+2] = fmaf(hv.z, w[j], acc[j*4+2]);
      acc[j*4+3] = fmaf(hv.w, w[j], acc[j*4+3]);
    }
  }
  __syncthreads();                     // GEMM1 reads of hT/Ws complete

  #pragma unroll
  for (int i = 0; i < 18; ++i)         // stage W2
    ((float4*)Ws)[t + 128*i] = ((const float4*)W2)[t + 128*i];
  #pragma unroll
  for (int j = 0; j < 12; ++j){        // mid = bn(lrelu(acc)) -> hT rows d0..
    int d = d0 + j;
    float s = g[d] * rsqrtf(var[d] + BN_EPS);
    float mu = mean[d], bt = beta[d];
    float4 m;
    m.x = (lrelu(acc[j*4+0]) - mu)*s + bt;
    m.y = (lrelu(acc[j*4+1]) - mu)*s + bt;
    m.z = (lrelu(acc[j*4+2]) - mu)*s + bt;
    m.w = (lrelu(acc[j*4+3]) - mu)*s + bt;
    *(float4*)&hT[d*68 + n0] = m;
  }
  __syncthreads();

  #pragma unroll
  for (int j = 0; j < 12; ++j){
    float bj = b2[d0+j];
    #pragma unroll
    for (int i = 0; i < 4; ++i) acc[j*4+i] = bj;
  }
  #pragma unroll 2
  for (int k = 0; k < 96; ++k){
    float4 hv = *(const float4*)&hT[k*68 + n0];
    const float* wr = &Ws[k*96 + d0];
    float w[12];
    *(float4*)&w[0] = *(const float4*)(wr);
    *(float4*)&w[4] = *(const float4*)(wr+4);
    *(float4*)&w[8] = *(const float4*)(wr+8);
    #pragma unroll
    for (int j = 0; j < 12; ++j){
      acc[j*4+0] = fmaf(hv.x, w[j], acc[j*4+0]);
      acc[j*4+1] = fmaf(hv.y, w[j], acc[j*4+1]);
      acc[j*4+2] = fmaf(hv.z, w[j], acc[j*4+2]);
      acc[j*4+3] = fmaf(hv.w, w[j], acc[j*4+3]);
    }
  }

  // direct global store: node (nbase+n0+i), dims d0..d0+11
  #pragma unroll
  for (int i = 0; i < 4; ++i){
    int node = nbase + n0 + i;
    if (node < N){
      float* op = hout + (size_t)node*96 + d0;
      float4 o;
      o.x = lrelu(acc[0*4+i]);  o.y = lrelu(acc[1*4+i]);
      o.z = lrelu(acc[2*4+i]);  o.w = lrelu(acc[3*4+i]);
      *(float4*)(op) = o;
      o.x = lrelu(acc[4*4+i]);  o.y = lrelu(acc[5*4+i]);
      o.z = lrelu(acc[6*4+i]);  o.w = lrelu(acc[7*4+i]);
      *(float4*)(op+4) = o;
      o.x = lrelu(acc[8*4+i]);  o.y = lrelu(acc[9*4+i]);
      o.z = lrelu(acc[10*4+i]); o.w = lrelu(acc[11*4+i]);
      *(float4*)(op+8) = o;
    }
  }
}

// ---------------- pooling bounds over sorted batch ----------------
__global__ __launch_bounds__(256) void bounds_k(const int* __restrict__ batch,
                                                int* __restrict__ go, int N, int G){
  int i = blockIdx.x*256 + threadIdx.x;
  if (i >= N) return;
  int b = batch[i];
  int prev = (i == 0) ? -1 : batch[i-1];
  for (int g = prev+1; g <= b; ++g) go[g] = i;
  if (i == N-1){
    for (int g = b+1; g <= G; ++g) go[g] = N;
  }
}

// ---------------- fused pool + cond MLP + concat + BN + fc --------------------
__global__ __launch_bounds__(384) void poolfinal_k(
    const float* __restrict__ h, const int* __restrict__ go,
    const float* __restrict__ cond,
    const float* __restrict__ cW1, const float* __restrict__ cb1,
    const float* __restrict__ cg, const float* __restrict__ cbeta,
    const float* __restrict__ cmean, const float* __restrict__ cvar,
    const float* __restrict__ cW2, const float* __restrict__ cb2,
    const float* __restrict__ bn_g, const float* __restrict__ bn_b,
    const float* __restrict__ bn_mean, const float* __restrict__ bn_var,
    const float* __restrict__ fcW, const float* __restrict__ fcb,
    float* __restrict__ out)
{
  __shared__ float ps[4][96];
  __shared__ float pl[96];
  int g = blockIdx.x, t = threadIdx.x;
  int s = t / 96, d = t - s*96;        // s in 0..3
  {
    float acc = 0.f;
    int nb = go[g], ne = go[g+1];
    for (int n = nb + s; n < ne; n += 4) acc += h[(size_t)n*96 + d];
    ps[s][d] = acc;
  }
  __syncthreads();
  if (t < 96) pl[t] = ps[0][t] + ps[1][t] + ps[2][t] + ps[3][t];
  __syncthreads();

  if (t < 64){
    float cin[7];
    #pragma unroll
    for (int j = 0; j < 7; ++j) cin[j] = cond[g*7+j];
    float c1[5];
    #pragma unroll
    for (int i = 0; i < 5; ++i){
      float a = cb1[i];
      #pragma unroll
      for (int j = 0; j < 7; ++j) a = fmaf(cin[j], cW1[j*5+i], a);
      float sc = cg[i] * rsqrtf(cvar[i] + BN_EPS);
      a = (a - cmean[i])*sc + cbeta[i];
      c1[i] = a > 0.f ? a : 0.f;
    }
    float c2[5];
    #pragma unroll
    for (int i = 0; i < 5; ++i){
      float a = cb2[i];
      #pragma unroll
      for (int j = 0; j < 5; ++j) a = fmaf(c1[j], cW2[j*5+i], a);
      c2[i] = a > 0.f ? a : 0.f;
    }
    float acc = fcb[t];
    #pragma unroll
    for (int j = 0; j < 5; ++j){
      float sc = bn_g[j] * rsqrtf(bn_var[j] + BN_EPS);
      float nb = (c2[j] - bn_mean[j])*sc + bn_b[j];
      acc = fmaf(nb, fcW[j*64 + t], acc);
    }
    for (int j = 5; j < 101; ++j){
      float vj = pl[j-5];
      float sc = bn_g[j] * rsqrtf(bn_var[j] + BN_EPS);
      float nb = (vj - bn_mean[j])*sc + bn_b[j];
      acc = fmaf(nb, fcW[j*64 + t], acc);
    }
    out[g*64 + t] = acc;
  }
}

// ---------------- launch ----------------

extern "C" void kernel_launch(void* const* d_in, const int* in_sizes, int n_in,
                              void* d_out, int out_size, void* d_ws, size_t ws_size,
                              hipStream_t stream)
{
  const float* x         = (const float*)d_in[0];
  const float* cond      = (const float*)d_in[1];
  const int*   ei        = (const int*)  d_in[2];
  const int*   batch     = (const int*)  d_in[3];
  const float* conv_W1   = (const float*)d_in[4];
  const float* conv_b1   = (const float*)d_in[5];
  const float* conv_g    = (const float*)d_in[6];
  const float* conv_beta = (const float*)d_in[7];
  const float* conv_mean = (const float*)d_in[8];
  const float* conv_var  = (const float*)d_in[9];
  const float* conv_W2   = (const float*)d_in[10];
  const float* conv_b2   = (const float*)d_in[11];
  const float* cW1       = (const float*)d_in[12];
  const float* cb1       = (const float*)d_in[13];
  const float* cg        = (const float*)d_in[14];
  const float* cbeta     = (const float*)d_in[15];
  const float* cmean     = (const float*)d_in[16];
  const float* cvar      = (const float*)d_in[17];
  const float* cW2       = (const float*)d_in[18];
  const float* cb2       = (const float*)d_in[19];
  const float* bn_g      = (const float*)d_in[20];
  const float* bn_b      = (const float*)d_in[21];
  const float* bn_mean   = (const float*)d_in[22];
  const float* bn_var    = (const float*)d_in[23];
  const float* fc_W      = (const float*)d_in[24];
  const float* fc_b      = (const float*)d_in[25];

  const int D = 96;
  int N = in_sizes[0] / D;
  int G = in_sizes[1] / 7;
  int E = in_sizes[2] / 2;
  const int* src = ei;
  const int* dst = ei + E;

  char* p = (char*)d_ws;
  auto carve = [&](size_t bytes)->void*{
    void* r = (void*)p; p += (bytes + 255) & ~(size_t)255; return r;
  };
  int*   off     = (int*)  carve((size_t)(N+1)*4);
  int*   bsum    = (int*)  carve(256*4);
  int*   bcnt    = (int*)  carve(512*4);
  int*   bkt_off = (int*)  carve(513*4);
  int*   gcur    = (int*)  carve(512*4);
  int2*  ebuf    = (int2*) carve((size_t)E*8);
  int*   srcs    = (int*)  carve((size_t)E*4);
  int*   go      = (int*)  carve((size_t)(G+1)*4);
  float* hA      = (float*)carve((size_t)N*D*4);
  float* hB      = (float*)carve((size_t)N*D*4);

  int gN = (N+255)/256, gEB = (E+EB-1)/EB;

  hipMemsetAsync(off,  0, (size_t)(N+1)*4, stream);
  hipMemsetAsync(bcnt, 0, 512*4, stream);
  hist2_k<<<gEB, 256, 0, stream>>>(dst, off, bcnt, E);
  scan1_k<<<gN, 256, 0, stream>>>(off, bsum, N);
  scan2_k<<<1,  256, 0, stream>>>(bsum, gN);
  scan3_k<<<gN, 256, 0, stream>>>(off, bsum, N, E);
  bscan_k<<<1,  512, 0, stream>>>(bcnt, bkt_off, gcur, E);
  bpart_k<<<gEB, 256, 0, stream>>>(src, dst, gcur, ebuf, E);
  bscat_k<<<512, 256, 0, stream>>>(ebuf, bkt_off, off, srcs, N);
  bounds_k<<<gN, 256, 0, stream>>>(batch, go, N, G);

  const float* hin = x;
  int nblk = (N+63)/64;
  for (int l = 0; l < 3; ++l){
    agg_k<<<(N+7)/8, 256, 0, stream>>>(hin, hB, off, srcs, N);
    mlp_mt_k<<<nblk, 128, 0, stream>>>(hB, hA,
        conv_W1 + (size_t)l*D*D, conv_b1 + l*D,
        conv_g + l*D, conv_beta + l*D, conv_mean + l*D, conv_var + l*D,
        conv_W2 + (size_t)l*D*D, conv_b2 + l*D, N);
    hin = hA;
  }

  poolfinal_k<<<G, 384, 0, stream>>>(hA, go, cond,
                                     cW1, cb1, cg, cbeta, cmean, cvar,
                                     cW2, cb2, bn_g, bn_b, bn_mean, bn_var,
                                     fc_W, fc_b, (float*)d_out);
}

// Round 11
// 427.779 us; speedup vs baseline: 1.3065x; 1.3065x over previous
//
#include <hip/hip_runtime.h>

#define BN_EPS 1e-5f

__device__ __forceinline__ float lrelu(float x){ return x > 0.f ? x : 0.2f*x; }

struct F3 { float x, y, z; };   // 12B -> global_load_dwordx3

typedef __attribute__((ext_vector_type(8))) short short8v;  // 8 bf16 (4 VGPR)
typedef __attribute__((ext_vector_type(4))) float f32x4;

#define EB 4096          // edges per partition block

// ---------------- merged histograms: node degree + bucket counts --------------
__global__ __launch_bounds__(256) void hist2_k(const int* __restrict__ dst,
                                               int* __restrict__ deg,
                                               int* __restrict__ bcnt, int E){
  __shared__ int bh[512];
  int t = threadIdx.x;
  bh[t] = 0; bh[t+256] = 0;
  __syncthreads();
  int e0 = blockIdx.x*EB;
  for (int i = 0; i < EB/256; ++i){
    int e = e0 + i*256 + t;
    if (e < E){
      int d = dst[e];
      atomicAdd(&deg[d], 1);
      atomicAdd(&bh[d >> 7], 1);
    }
  }
  __syncthreads();
  if (bh[t])     atomicAdd(&bcnt[t],     bh[t]);
  if (bh[t+256]) atomicAdd(&bcnt[t+256], bh[t+256]);
}

// ---------------- CSR offset scan ----------------
__global__ __launch_bounds__(256) void scan1_k(int* __restrict__ degoff,
                                               int* __restrict__ bsum, int N){
  __shared__ int s[256];
  int t = threadIdx.x, i = blockIdx.x*256 + t;
  int v = (i < N) ? degoff[i] : 0;
  s[t] = v; __syncthreads();
  int x = v;
  for (int d = 1; d < 256; d <<= 1){
    int y = (t >= d) ? s[t-d] : 0;
    __syncthreads();
    x += y; s[t] = x;
    __syncthreads();
  }
  if (i < N) degoff[i] = x - v;
  if (t == 255) bsum[blockIdx.x] = x;
}

__global__ __launch_bounds__(256) void scan2_k(int* __restrict__ bsum, int nb){
  __shared__ int s[256];
  int t = threadIdx.x;
  int v = (t < nb) ? bsum[t] : 0;
  s[t] = v; __syncthreads();
  int x = v;
  for (int d = 1; d < 256; d <<= 1){
    int y = (t >= d) ? s[t-d] : 0;
    __syncthreads();
    x += y; s[t] = x;
    __syncthreads();
  }
  if (t < nb) bsum[t] = x - v;
}

__global__ __launch_bounds__(256) void scan3_k(int* __restrict__ off,
                                               const int* __restrict__ bsum,
                                               int N, int E){
  int i = blockIdx.x*256 + threadIdx.x;
  if (i < N) off[i] += bsum[blockIdx.x];
  if (i == 0) off[N] = E;
}

// ---------------- bucketed edge partition ----------------
__global__ __launch_bounds__(512) void bscan_k(const int* __restrict__ bcnt,
                                               int* __restrict__ bkt_off,
                                               int* __restrict__ gcur, int E){
  __shared__ int s[512];
  int t = threadIdx.x;
  int v = bcnt[t];
  s[t] = v; __syncthreads();
  int x = v;
  for (int d = 1; d < 512; d <<= 1){
    int y = (t >= d) ? s[t-d] : 0;
    __syncthreads();
    x += y; s[t] = x;
    __syncthreads();
  }
  bkt_off[t] = x - v;
  gcur[t]    = x - v;
  if (t == 511) bkt_off[512] = E;
}

__global__ __launch_bounds__(256) void bpart_k(const int* __restrict__ src,
                                               const int* __restrict__ dst,
                                               int* __restrict__ gcur,
                                               int2* __restrict__ ebuf, int E){
  __shared__ int bh[512];
  __shared__ int base[512];
  int t = threadIdx.x;
  bh[t] = 0; bh[t+256] = 0;
  __syncthreads();
  int e0 = blockIdx.x*EB;
  for (int i = 0; i < EB/256; ++i){
    int e = e0 + i*256 + t;
    if (e < E) atomicAdd(&bh[dst[e] >> 7], 1);
  }
  __syncthreads();
  #pragma unroll
  for (int h = 0; h < 2; ++h){
    int b = t + h*256;
    base[b] = bh[b] ? atomicAdd(&gcur[b], bh[b]) : 0;
  }
  __syncthreads();
  for (int i = 0; i < EB/256; ++i){
    int e = e0 + i*256 + t;
    if (e < E){
      int s = src[e], d = dst[e];
      int p = atomicAdd(&base[d >> 7], 1);
      ebuf[p] = make_int2(s, d);
    }
  }
}

__global__ __launch_bounds__(256) void bscat_k(const int2* __restrict__ ebuf,
                                               const int* __restrict__ bkt_off,
                                               const int* __restrict__ off,
                                               int* __restrict__ srcs, int N){
  __shared__ int lcur[128];
  int b = blockIdx.x, t = threadIdx.x;
  int node_lo = b << 7;
  if (t < 128){
    int n = node_lo + t;
    lcur[t] = (n < N) ? off[n] : 0;
  }
  __syncthreads();
  int eb = bkt_off[b], ee = bkt_off[b+1];
  for (int e = eb + t; e < ee; e += 256){
    int2 sd = ebuf[e];
    int p = atomicAdd(&lcur[sd.y - node_lo], 1);
    srcs[p] = sd.x;
  }
}

// ---------------- GIN aggregation: lane owns feats 3ln..3ln+2 -----------------
__global__ __launch_bounds__(256) void agg_k(const float* __restrict__ hin,
                                             float* __restrict__ hout,
                                             const int* __restrict__ off,
                                             const int* __restrict__ srcs, int N){
  int node = blockIdx.x*8 + (threadIdx.x >> 5);
  int ln = threadIdx.x & 31;
  if (node >= N) return;
  F3 a = *((const F3*)(hin + (size_t)node*96) + ln);
  float bx = 0.f, by = 0.f, bz = 0.f;
  int jb = off[node], je = off[node+1];
  int j = jb;
  for (; j+1 < je; j += 2){
    int s0 = srcs[j], s1 = srcs[j+1];
    F3 q0 = *((const F3*)(hin + (size_t)s0*96) + ln);
    F3 q1 = *((const F3*)(hin + (size_t)s1*96) + ln);
    a.x += q0.x; a.y += q0.y; a.z += q0.z;
    bx  += q1.x; by  += q1.y; bz  += q1.z;
  }
  if (j < je){
    int s0 = srcs[j];
    F3 q0 = *((const F3*)(hin + (size_t)s0*96) + ln);
    a.x += q0.x; a.y += q0.y; a.z += q0.z;
  }
  a.x += bx; a.y += by; a.z += bz;
  *((F3*)(hout + (size_t)node*96) + ln) = a;
}

// ---------------- W -> MFMA fragment pre-pack (split-bf16 hi/lo) --------------
// Fragment order: idx = ((kb*6+nt)*64 + lane)*8 + j, mapping
// k = 32*kb + 8*(lane>>4) + j, n = 16*nt + (lane&15)  (same k-map as A frags).
__global__ __launch_bounds__(256) void wprep_k(const float* __restrict__ W1b,
                                               const float* __restrict__ W2b,
                                               short* __restrict__ Wpk){
  int mat = blockIdx.x;                 // 0..5 : {l0W1,l0W2,l1W1,l1W2,l2W1,l2W2}
  int layer = mat >> 1, which = mat & 1;
  const float* src = (which ? W2b : W1b) + (size_t)layer*9216;
  short* hi = Wpk + (size_t)mat*18432;
  short* lo = hi + 9216;
  for (int i = threadIdx.x; i < 9216; i += 256){
    int j = i & 7, lane = (i >> 3) & 63, grp = i >> 9;
    int kb = grp / 6, nt = grp - 6*kb;
    int k = 32*kb + 8*(lane>>4) + j;
    int n = 16*nt + (lane&15);
    float v = src[k*96 + n];
    unsigned b = __float_as_uint(v);
    unsigned short hb = (unsigned short)(b >> 16);
    float hf = __uint_as_float((unsigned)hb << 16);
    float lof = v - hf;
    hi[i] = (short)hb;
    lo[i] = (short)(__float_as_uint(lof) >> 16);
  }
}

// ---------------- MFMA MLP: split-bf16, 64-node tile, 4 waves -----------------
// Wave w owns rows 16w..16w+15. A-frags from hT (pad 97 -> conflict-free b128).
// B-frags: prepacked global 16B loads. 9 mfma per 16x16 C-tile (hi*hi+hi*lo+lo*hi).
__global__ __launch_bounds__(256) void mlp_mfma_k(
    const float* __restrict__ hin, float* __restrict__ hout,
    const short* __restrict__ Whi1, const short* __restrict__ Wlo1,
    const short* __restrict__ Whi2, const short* __restrict__ Wlo2,
    const float* __restrict__ b1, const float* __restrict__ g,
    const float* __restrict__ beta, const float* __restrict__ mean,
    const float* __restrict__ var, const float* __restrict__ b2, int N)
{
  __shared__ float hT[64*97];          // 24.8 KB
  int t = threadIdx.x;
  int nbase = blockIdx.x * 64;
  int lim = (N - nbase) * 96;
  const float* hbase = hin + (size_t)nbase*96;

  #pragma unroll
  for (int i = 0; i < 24; ++i){        // coalesced stage-in
    int tid = t + 256*i;
    float v = (tid < lim) ? hbase[tid] : 0.f;
    int n = tid / 96, k = tid - n*96;
    hT[n*97 + k] = v;
  }
  __syncthreads();

  int l = t & 63, w = t >> 6;
  int kgrp = l >> 4;
  int arow = 16*w + (l & 15);          // A row (M) for this lane
  int col  = l & 15;                   // B/C col within nt tile

  // ---- A fragments (hi/lo) for GEMM1 ----
  short8v ah[3], al[3];
  #pragma unroll
  for (int kb = 0; kb < 3; ++kb){
    const float* ap = &hT[arow*97 + 32*kb + 8*kgrp];
    #pragma unroll
    for (int j = 0; j < 8; ++j){
      float v = ap[j];
      unsigned bits = __float_as_uint(v);
      unsigned short hb = (unsigned short)(bits >> 16);
      float hf = __uint_as_float((unsigned)hb << 16);
      unsigned short lb = (unsigned short)(__float_as_uint(v - hf) >> 16);
      ah[kb][j] = (short)hb;
      al[kb][j] = (short)lb;
    }
  }

  // ---- GEMM1 + BN + lrelu (results in regs) ----
  float mid[6][4];
  {
    const short8v* BH = (const short8v*)Whi1;
    const short8v* BL = (const short8v*)Wlo1;
    #pragma unroll
    for (int nt = 0; nt < 6; ++nt){
      int d = 16*nt + col;
      float bv = b1[d];
      f32x4 acc; acc[0]=bv; acc[1]=bv; acc[2]=bv; acc[3]=bv;
      #pragma unroll
      for (int kb = 0; kb < 3; ++kb){
        short8v bh = BH[(kb*6 + nt)*64 + l];
        short8v bl = BL[(kb*6 + nt)*64 + l];
        acc = __builtin_amdgcn_mfma_f32_16x16x32_bf16(ah[kb], bh, acc, 0,0,0);
        acc = __builtin_amdgcn_mfma_f32_16x16x32_bf16(ah[kb], bl, acc, 0,0,0);
        acc = __builtin_amdgcn_mfma_f32_16x16x32_bf16(al[kb], bh, acc, 0,0,0);
      }
      float s  = g[d] * rsqrtf(var[d] + BN_EPS);
      float mu = mean[d], bt = beta[d];
      #pragma unroll
      for (int r = 0; r < 4; ++r)
        mid[nt][r] = (lrelu(acc[r]) - mu)*s + bt;
    }
  }
  __syncthreads();                     // all hT reads (A frags) done

  // ---- mid -> hT in C layout: row = 16w + 4*kgrp + r, col = 16nt+col ----
  #pragma unroll
  for (int nt = 0; nt < 6; ++nt)
    #pragma unroll
    for (int r = 0; r < 4; ++r)
      hT[(16*w + 4*kgrp + r)*97 + 16*nt + col] = mid[nt][r];
  __syncthreads();

  // ---- A fragments for GEMM2 ----
  #pragma unroll
  for (int kb = 0; kb < 3; ++kb){
    const float* ap = &hT[arow*97 + 32*kb + 8*kgrp];
    #pragma unroll
    for (int j = 0; j < 8; ++j){
      float v = ap[j];
      unsigned bits = __float_as_uint(v);
      unsigned short hb = (unsigned short)(bits >> 16);
      float hf = __uint_as_float((unsigned)hb << 16);
      unsigned short lb = (unsigned short)(__float_as_uint(v - hf) >> 16);
      ah[kb][j] = (short)hb;
      al[kb][j] = (short)lb;
    }
  }

  // ---- GEMM2 + lrelu ----
  float outr[6][4];
  {
    const short8v* BH = (const short8v*)Whi2;
    const short8v* BL = (const short8v*)Wlo2;
    #pragma unroll
    for (int nt = 0; nt < 6; ++nt){
      float bv = b2[16*nt + col];
      f32x4 acc; acc[0]=bv; acc[1]=bv; acc[2]=bv; acc[3]=bv;
      #pragma unroll
      for (int kb = 0; kb < 3; ++kb){
        short8v bh = BH[(kb*6 + nt)*64 + l];
        short8v bl = BL[(kb*6 + nt)*64 + l];
        acc = __builtin_amdgcn_mfma_f32_16x16x32_bf16(ah[kb], bh, acc, 0,0,0);
        acc = __builtin_amdgcn_mfma_f32_16x16x32_bf16(ah[kb], bl, acc, 0,0,0);
        acc = __builtin_amdgcn_mfma_f32_16x16x32_bf16(al[kb], bh, acc, 0,0,0);
      }
      #pragma unroll
      for (int r = 0; r < 4; ++r) outr[nt][r] = lrelu(acc[r]);
    }
  }
  __syncthreads();                     // all hT reads done before overwrite

  #pragma unroll
  for (int nt = 0; nt < 6; ++nt)
    #pragma unroll
    for (int r = 0; r < 4; ++r)
      hT[(16*w + 4*kgrp + r)*97 + 16*nt + col] = outr[nt][r];
  __syncthreads();

  float* obase = hout + (size_t)nbase*96;
  #pragma unroll
  for (int i = 0; i < 24; ++i){        // coalesced store
    int tid = t + 256*i;
    int n = tid / 96, k = tid - n*96;
    if (tid < lim) obase[tid] = hT[n*97 + k];
  }
}

// ---------------- pooling bounds over sorted batch ----------------
__global__ __launch_bounds__(256) void bounds_k(const int* __restrict__ batch,
                                                int* __restrict__ go, int N, int G){
  int i = blockIdx.x*256 + threadIdx.x;
  if (i >= N) return;
  int b = batch[i];
  int prev = (i == 0) ? -1 : batch[i-1];
  for (int g = prev+1; g <= b; ++g) go[g] = i;
  if (i == N-1){
    for (int g = b+1; g <= G; ++g) go[g] = N;
  }
}

// ---------------- fused pool + cond MLP + concat + BN + fc --------------------
__global__ __launch_bounds__(384) void poolfinal_k(
    const float* __restrict__ h, const int* __restrict__ go,
    const float* __restrict__ cond,
    const float* __restrict__ cW1, const float* __restrict__ cb1,
    const float* __restrict__ cg, const float* __restrict__ cbeta,
    const float* __restrict__ cmean, const float* __restrict__ cvar,
    const float* __restrict__ cW2, const float* __restrict__ cb2,
    const float* __restrict__ bn_g, const float* __restrict__ bn_b,
    const float* __restrict__ bn_mean, const float* __restrict__ bn_var,
    const float* __restrict__ fcW, const float* __restrict__ fcb,
    float* __restrict__ out)
{
  __shared__ float ps[4][96];
  __shared__ float pl[96];
  int g = blockIdx.x, t = threadIdx.x;
  int s = t / 96, d = t - s*96;
  {
    float acc = 0.f;
    int nb = go[g], ne = go[g+1];
    for (int n = nb + s; n < ne; n += 4) acc += h[(size_t)n*96 + d];
    ps[s][d] = acc;
  }
  __syncthreads();
  if (t < 96) pl[t] = ps[0][t] + ps[1][t] + ps[2][t] + ps[3][t];
  __syncthreads();

  if (t < 64){
    float cin[7];
    #pragma unroll
    for (int j = 0; j < 7; ++j) cin[j] = cond[g*7+j];
    float c1[5];
    #pragma unroll
    for (int i = 0; i < 5; ++i){
      float a = cb1[i];
      #pragma unroll
      for (int j = 0; j < 7; ++j) a = fmaf(cin[j], cW1[j*5+i], a);
      float sc = cg[i] * rsqrtf(cvar[i] + BN_EPS);
      a = (a - cmean[i])*sc + cbeta[i];
      c1[i] = a > 0.f ? a : 0.f;
    }
    float c2[5];
    #pragma unroll
    for (int i = 0; i < 5; ++i){
      float a = cb2[i];
      #pragma unroll
      for (int j = 0; j < 5; ++j) a = fmaf(c1[j], cW2[j*5+i], a);
      c2[i] = a > 0.f ? a : 0.f;
    }
    float acc = fcb[t];
    #pragma unroll
    for (int j = 0; j < 5; ++j){
      float sc = bn_g[j] * rsqrtf(bn_var[j] + BN_EPS);
      float nb = (c2[j] - bn_mean[j])*sc + bn_b[j];
      acc = fmaf(nb, fcW[j*64 + t], acc);
    }
    for (int j = 5; j < 101; ++j){
      float vj = pl[j-5];
      float sc = bn_g[j] * rsqrtf(bn_var[j] + BN_EPS);
      float nb = (vj - bn_mean[j])*sc + bn_b[j];
      acc = fmaf(nb, fcW[j*64 + t], acc);
    }
    out[g*64 + t] = acc;
  }
}

// ---------------- launch ----------------

extern "C" void kernel_launch(void* const* d_in, const int* in_sizes, int n_in,
                              void* d_out, int out_size, void* d_ws, size_t ws_size,
                              hipStream_t stream)
{
  const float* x         = (const float*)d_in[0];
  const float* cond      = (const float*)d_in[1];
  const int*   ei        = (const int*)  d_in[2];
  const int*   batch     = (const int*)  d_in[3];
  const float* conv_W1   = (const float*)d_in[4];
  const float* conv_b1   = (const float*)d_in[5];
  const float* conv_g    = (const float*)d_in[6];
  const float* conv_beta = (const float*)d_in[7];
  const float* conv_mean = (const float*)d_in[8];
  const float* conv_var  = (const float*)d_in[9];
  const float* conv_W2   = (const float*)d_in[10];
  const float* conv_b2   = (const float*)d_in[11];
  const float* cW1       = (const float*)d_in[12];
  const float* cb1       = (const float*)d_in[13];
  const float* cg        = (const float*)d_in[14];
  const float* cbeta     = (const float*)d_in[15];
  const float* cmean     = (const float*)d_in[16];
  const float* cvar      = (const float*)d_in[17];
  const float* cW2       = (const float*)d_in[18];
  const float* cb2       = (const float*)d_in[19];
  const float* bn_g      = (const float*)d_in[20];
  const float* bn_b      = (const float*)d_in[21];
  const float* bn_mean   = (const float*)d_in[22];
  const float* bn_var    = (const float*)d_in[23];
  const float* fc_W      = (const float*)d_in[24];
  const float* fc_b      = (const float*)d_in[25];

  const int D = 96;
  int N = in_sizes[0] / D;
  int G = in_sizes[1] / 7;
  int E = in_sizes[2] / 2;
  const int* src = ei;
  const int* dst = ei + E;

  char* p = (char*)d_ws;
  auto carve = [&](size_t bytes)->void*{
    void* r = (void*)p; p += (bytes + 255) & ~(size_t)255; return r;
  };
  int*   off     = (int*)  carve((size_t)(N+1)*4);
  int*   bsum    = (int*)  carve(256*4);
  int*   bcnt    = (int*)  carve(512*4);
  int*   bkt_off = (int*)  carve(513*4);
  int*   gcur    = (int*)  carve(512*4);
  int2*  ebuf    = (int2*) carve((size_t)E*8);
  int*   srcs    = (int*)  carve((size_t)E*4);
  int*   go      = (int*)  carve((size_t)(G+1)*4);
  short* Wpk     = (short*)carve(6*18432*2);
  float* hA      = (float*)carve((size_t)N*D*4);
  float* hB      = (float*)carve((size_t)N*D*4);

  int gN = (N+255)/256, gEB = (E+EB-1)/EB;

  hipMemsetAsync(off,  0, (size_t)(N+1)*4, stream);
  hipMemsetAsync(bcnt, 0, 512*4, stream);
  wprep_k<<<6, 256, 0, stream>>>(conv_W1, conv_W2, Wpk);
  hist2_k<<<gEB, 256, 0, stream>>>(dst, off, bcnt, E);
  scan1_k<<<gN, 256, 0, stream>>>(off, bsum, N);
  scan2_k<<<1,  256, 0, stream>>>(bsum, gN);
  scan3_k<<<gN, 256, 0, stream>>>(off, bsum, N, E);
  bscan_k<<<1,  512, 0, stream>>>(bcnt, bkt_off, gcur, E);
  bpart_k<<<gEB, 256, 0, stream>>>(src, dst, gcur, ebuf, E);
  bscat_k<<<512, 256, 0, stream>>>(ebuf, bkt_off, off, srcs, N);
  bounds_k<<<gN, 256, 0, stream>>>(batch, go, N, G);

  const float* hin = x;
  int nblk = (N+63)/64;
  for (int l = 0; l < 3; ++l){
    agg_k<<<(N+7)/8, 256, 0, stream>>>(hin, hB, off, srcs, N);
    const short* Whi1 = Wpk + (size_t)(2*l)  *18432;
    const short* Wlo1 = Whi1 + 9216;
    const short* Whi2 = Wpk + (size_t)(2*l+1)*18432;
    const short* Wlo2 = Whi2 + 9216;
    mlp_mfma_k<<<nblk, 256, 0, stream>>>(hB, hA, Whi1, Wlo1, Whi2, Wlo2,
        conv_b1 + l*D, conv_g + l*D, conv_beta + l*D, conv_mean + l*D,
        conv_var + l*D, conv_b2 + l*D, N);
    hin = hA;
  }

  poolfinal_k<<<G, 384, 0, stream>>>(hA, go, cond,
                                     cW1, cb1, cg, cbeta, cmean, cvar,
                                     cW2, cb2, bn_g, bn_b, bn_mean, bn_var,
                                     fc_W, fc_b, (float*)d_out);
}

// Round 12
// 420.942 us; speedup vs baseline: 1.3277x; 1.0162x over previous
//
#include <hip/hip_runtime.h>

#define BN_EPS 1e-5f

__device__ __forceinline__ float lrelu(float x){ return x > 0.f ? x : 0.2f*x; }

struct F3 { float x, y, z; };   // 12B -> global_load_dwordx3

typedef __attribute__((ext_vector_type(8))) short short8v;  // 8 bf16 (4 VGPR)
typedef __attribute__((ext_vector_type(4))) float f32x4;

#define EB 4096          // edges per partition block

// ---------------- merged histograms: node degree + bucket counts --------------
__global__ __launch_bounds__(256) void hist2_k(const int* __restrict__ dst,
                                               int* __restrict__ deg,
                                               int* __restrict__ bcnt, int E){
  __shared__ int bh[512];
  int t = threadIdx.x;
  bh[t] = 0; bh[t+256] = 0;
  __syncthreads();
  int e0 = blockIdx.x*EB;
  for (int i = 0; i < EB/256; ++i){
    int e = e0 + i*256 + t;
    if (e < E){
      int d = dst[e];
      atomicAdd(&deg[d], 1);
      atomicAdd(&bh[d >> 7], 1);
    }
  }
  __syncthreads();
  if (bh[t])     atomicAdd(&bcnt[t],     bh[t]);
  if (bh[t+256]) atomicAdd(&bcnt[t+256], bh[t+256]);
}

// ---------------- CSR offset scan ----------------
__global__ __launch_bounds__(256) void scan1_k(int* __restrict__ degoff,
                                               int* __restrict__ bsum, int N){
  __shared__ int s[256];
  int t = threadIdx.x, i = blockIdx.x*256 + t;
  int v = (i < N) ? degoff[i] : 0;
  s[t] = v; __syncthreads();
  int x = v;
  for (int d = 1; d < 256; d <<= 1){
    int y = (t >= d) ? s[t-d] : 0;
    __syncthreads();
    x += y; s[t] = x;
    __syncthreads();
  }
  if (i < N) degoff[i] = x - v;
  if (t == 255) bsum[blockIdx.x] = x;
}

__global__ __launch_bounds__(256) void scan2_k(int* __restrict__ bsum, int nb){
  __shared__ int s[256];
  int t = threadIdx.x;
  int v = (t < nb) ? bsum[t] : 0;
  s[t] = v; __syncthreads();
  int x = v;
  for (int d = 1; d < 256; d <<= 1){
    int y = (t >= d) ? s[t-d] : 0;
    __syncthreads();
    x += y; s[t] = x;
    __syncthreads();
  }
  if (t < nb) bsum[t] = x - v;
}

__global__ __launch_bounds__(256) void scan3_k(int* __restrict__ off,
                                               const int* __restrict__ bsum,
                                               int N, int E){
  int i = blockIdx.x*256 + threadIdx.x;
  if (i < N) off[i] += bsum[blockIdx.x];
  if (i == 0) off[N] = E;
}

// ---------------- bucketed edge partition ----------------
__global__ __launch_bounds__(512) void bscan_k(const int* __restrict__ bcnt,
                                               int* __restrict__ bkt_off,
                                               int* __restrict__ gcur, int E){
  __shared__ int s[512];
  int t = threadIdx.x;
  int v = bcnt[t];
  s[t] = v; __syncthreads();
  int x = v;
  for (int d = 1; d < 512; d <<= 1){
    int y = (t >= d) ? s[t-d] : 0;
    __syncthreads();
    x += y; s[t] = x;
    __syncthreads();
  }
  bkt_off[t] = x - v;
  gcur[t]    = x - v;
  if (t == 511) bkt_off[512] = E;
}

__global__ __launch_bounds__(256) void bpart_k(const int* __restrict__ src,
                                               const int* __restrict__ dst,
                                               int* __restrict__ gcur,
                                               int2* __restrict__ ebuf, int E){
  __shared__ int bh[512];
  __shared__ int base[512];
  int t = threadIdx.x;
  bh[t] = 0; bh[t+256] = 0;
  __syncthreads();
  int e0 = blockIdx.x*EB;
  for (int i = 0; i < EB/256; ++i){
    int e = e0 + i*256 + t;
    if (e < E) atomicAdd(&bh[dst[e] >> 7], 1);
  }
  __syncthreads();
  #pragma unroll
  for (int h = 0; h < 2; ++h){
    int b = t + h*256;
    base[b] = bh[b] ? atomicAdd(&gcur[b], bh[b]) : 0;
  }
  __syncthreads();
  for (int i = 0; i < EB/256; ++i){
    int e = e0 + i*256 + t;
    if (e < E){
      int s = src[e], d = dst[e];
      int p = atomicAdd(&base[d >> 7], 1);
      ebuf[p] = make_int2(s, d);
    }
  }
}

__global__ __launch_bounds__(256) void bscat_k(const int2* __restrict__ ebuf,
                                               const int* __restrict__ bkt_off,
                                               const int* __restrict__ off,
                                               int* __restrict__ srcs, int N){
  __shared__ int lcur[128];
  int b = blockIdx.x, t = threadIdx.x;
  int node_lo = b << 7;
  if (t < 128){
    int n = node_lo + t;
    lcur[t] = (n < N) ? off[n] : 0;
  }
  __syncthreads();
  int eb = bkt_off[b], ee = bkt_off[b+1];
  for (int e = eb + t; e < ee; e += 256){
    int2 sd = ebuf[e];
    int p = atomicAdd(&lcur[sd.y - node_lo], 1);
    srcs[p] = sd.x;
  }
}

// ---------------- GIN aggregation: 4-deep unroll, 8 gathers/wave in flight ----
__global__ __launch_bounds__(256) void agg_k(const float* __restrict__ hin,
                                             float* __restrict__ hout,
                                             const int* __restrict__ off,
                                             const int* __restrict__ srcs, int N){
  int node = blockIdx.x*8 + (threadIdx.x >> 5);
  int ln = threadIdx.x & 31;
  if (node >= N) return;
  F3 a = *((const F3*)(hin + (size_t)node*96) + ln);
  float bx=0.f, by=0.f, bz=0.f, cx=0.f, cy=0.f, cz=0.f, dx=0.f, dy=0.f, dz=0.f;
  int jb = off[node], je = off[node+1];
  int j = jb;
  for (; j+3 < je; j += 4){
    int s0 = srcs[j], s1 = srcs[j+1], s2 = srcs[j+2], s3 = srcs[j+3];
    F3 q0 = *((const F3*)(hin + (size_t)s0*96) + ln);
    F3 q1 = *((const F3*)(hin + (size_t)s1*96) + ln);
    F3 q2 = *((const F3*)(hin + (size_t)s2*96) + ln);
    F3 q3 = *((const F3*)(hin + (size_t)s3*96) + ln);
    a.x += q0.x; a.y += q0.y; a.z += q0.z;
    bx  += q1.x; by  += q1.y; bz  += q1.z;
    cx  += q2.x; cy  += q2.y; cz  += q2.z;
    dx  += q3.x; dy  += q3.y; dz  += q3.z;
  }
  for (; j < je; ++j){
    int s0 = srcs[j];
    F3 q0 = *((const F3*)(hin + (size_t)s0*96) + ln);
    a.x += q0.x; a.y += q0.y; a.z += q0.z;
  }
  a.x += bx + cx + dx;
  a.y += by + cy + dy;
  a.z += bz + cz + dz;
  *((F3*)(hout + (size_t)node*96) + ln) = a;
}

// ---------------- W -> MFMA fragment pre-pack (split-bf16 hi/lo) --------------
// Fragment order: idx = ((kb*6+nt)*64 + lane)*8 + j, mapping
// k = 32*kb + 8*(lane>>4) + j, n = 16*nt + (lane&15)  (same k-map as A frags).
__global__ __launch_bounds__(256) void wprep_k(const float* __restrict__ W1b,
                                               const float* __restrict__ W2b,
                                               short* __restrict__ Wpk){
  int mat = blockIdx.x;                 // 0..5 : {l0W1,l0W2,l1W1,l1W2,l2W1,l2W2}
  int layer = mat >> 1, which = mat & 1;
  const float* src = (which ? W2b : W1b) + (size_t)layer*9216;
  short* hi = Wpk + (size_t)mat*18432;
  short* lo = hi + 9216;
  for (int i = threadIdx.x; i < 9216; i += 256){
    int j = i & 7, lane = (i >> 3) & 63, grp = i >> 9;
    int kb = grp / 6, nt = grp - 6*kb;
    int k = 32*kb + 8*(lane>>4) + j;
    int n = 16*nt + (lane&15);
    float v = src[k*96 + n];
    unsigned b = __float_as_uint(v);
    unsigned short hb = (unsigned short)(b >> 16);
    float hf = __uint_as_float((unsigned)hb << 16);
    float lof = v - hf;
    hi[i] = (short)hb;
    lo[i] = (short)(__float_as_uint(lof) >> 16);
  }
}

// ---------------- MFMA MLP: split-bf16, 64-node tile, 4 waves -----------------
__global__ __launch_bounds__(256) void mlp_mfma_k(
    const float* __restrict__ hin, float* __restrict__ hout,
    const short* __restrict__ Whi1, const short* __restrict__ Wlo1,
    const short* __restrict__ Whi2, const short* __restrict__ Wlo2,
    const float* __restrict__ b1, const float* __restrict__ g,
    const float* __restrict__ beta, const float* __restrict__ mean,
    const float* __restrict__ var, const float* __restrict__ b2, int N)
{
  __shared__ float hT[64*97];          // 24.8 KB
  int t = threadIdx.x;
  int nbase = blockIdx.x * 64;
  int lim = (N - nbase) * 96;
  const float* hbase = hin + (size_t)nbase*96;

  #pragma unroll
  for (int i = 0; i < 24; ++i){        // coalesced stage-in
    int tid = t + 256*i;
    float v = (tid < lim) ? hbase[tid] : 0.f;
    int n = tid / 96, k = tid - n*96;
    hT[n*97 + k] = v;
  }
  __syncthreads();

  int l = t & 63, w = t >> 6;
  int kgrp = l >> 4;
  int arow = 16*w + (l & 15);          // A row (M) for this lane
  int col  = l & 15;                   // B/C col within nt tile

  // ---- A fragments (hi/lo) for GEMM1 ----
  short8v ah[3], al[3];
  #pragma unroll
  for (int kb = 0; kb < 3; ++kb){
    const float* ap = &hT[arow*97 + 32*kb + 8*kgrp];
    #pragma unroll
    for (int j = 0; j < 8; ++j){
      float v = ap[j];
      unsigned bits = __float_as_uint(v);
      unsigned short hb = (unsigned short)(bits >> 16);
      float hf = __uint_as_float((unsigned)hb << 16);
      unsigned short lb = (unsigned short)(__float_as_uint(v - hf) >> 16);
      ah[kb][j] = (short)hb;
      al[kb][j] = (short)lb;
    }
  }

  // ---- GEMM1 + BN + lrelu (results in regs) ----
  float mid[6][4];
  {
    const short8v* BH = (const short8v*)Whi1;
    const short8v* BL = (const short8v*)Wlo1;
    #pragma unroll
    for (int nt = 0; nt < 6; ++nt){
      int d = 16*nt + col;
      float bv = b1[d];
      f32x4 acc; acc[0]=bv; acc[1]=bv; acc[2]=bv; acc[3]=bv;
      #pragma unroll
      for (int kb = 0; kb < 3; ++kb){
        short8v bh = BH[(kb*6 + nt)*64 + l];
        short8v bl = BL[(kb*6 + nt)*64 + l];
        acc = __builtin_amdgcn_mfma_f32_16x16x32_bf16(ah[kb], bh, acc, 0,0,0);
        acc = __builtin_amdgcn_mfma_f32_16x16x32_bf16(ah[kb], bl, acc, 0,0,0);
        acc = __builtin_amdgcn_mfma_f32_16x16x32_bf16(al[kb], bh, acc, 0,0,0);
      }
      float s  = g[d] * rsqrtf(var[d] + BN_EPS);
      float mu = mean[d], bt = beta[d];
      #pragma unroll
      for (int r = 0; r < 4; ++r)
        mid[nt][r] = (lrelu(acc[r]) - mu)*s + bt;
    }
  }
  __syncthreads();                     // all hT reads (A frags) done

  // ---- mid -> hT in C layout: row = 16w + 4*kgrp + r, col = 16nt+col ----
  #pragma unroll
  for (int nt = 0; nt < 6; ++nt)
    #pragma unroll
    for (int r = 0; r < 4; ++r)
      hT[(16*w + 4*kgrp + r)*97 + 16*nt + col] = mid[nt][r];
  __syncthreads();

  // ---- A fragments for GEMM2 ----
  #pragma unroll
  for (int kb = 0; kb < 3; ++kb){
    const float* ap = &hT[arow*97 + 32*kb + 8*kgrp];
    #pragma unroll
    for (int j = 0; j < 8; ++j){
      float v = ap[j];
      unsigned bits = __float_as_uint(v);
      unsigned short hb = (unsigned short)(bits >> 16);
      float hf = __uint_as_float((unsigned)hb << 16);
      unsigned short lb = (unsigned short)(__float_as_uint(v - hf) >> 16);
      ah[kb][j] = (short)hb;
      al[kb][j] = (short)lb;
    }
  }

  // ---- GEMM2 + lrelu ----
  float outr[6][4];
  {
    const short8v* BH = (const short8v*)Whi2;
    const short8v* BL = (const short8v*)Wlo2;
    #pragma unroll
    for (int nt = 0; nt < 6; ++nt){
      float bv = b2[16*nt + col];
      f32x4 acc; acc[0]=bv; acc[1]=bv; acc[2]=bv; acc[3]=bv;
      #pragma unroll
      for (int kb = 0; kb < 3; ++kb){
        short8v bh = BH[(kb*6 + nt)*64 + l];
        short8v bl = BL[(kb*6 + nt)*64 + l];
        acc = __builtin_amdgcn_mfma_f32_16x16x32_bf16(ah[kb], bh, acc, 0,0,0);
        acc = __builtin_amdgcn_mfma_f32_16x16x32_bf16(ah[kb], bl, acc, 0,0,0);
        acc = __builtin_amdgcn_mfma_f32_16x16x32_bf16(al[kb], bh, acc, 0,0,0);
      }
      #pragma unroll
      for (int r = 0; r < 4; ++r) outr[nt][r] = lrelu(acc[r]);
    }
  }
  __syncthreads();                     // all hT reads done before overwrite

  #pragma unroll
  for (int nt = 0; nt < 6; ++nt)
    #pragma unroll
    for (int r = 0; r < 4; ++r)
      hT[(16*w + 4*kgrp + r)*97 + 16*nt + col] = outr[nt][r];
  __syncthreads();

  float* obase = hout + (size_t)nbase*96;
  #pragma unroll
  for (int i = 0; i < 24; ++i){        // coalesced store
    int tid = t + 256*i;
    int n = tid / 96, k = tid - n*96;
    if (tid < lim) obase[tid] = hT[n*97 + k];
  }
}

// ---------------- pooling bounds over sorted batch ----------------
__global__ __launch_bounds__(256) void bounds_k(const int* __restrict__ batch,
                                                int* __restrict__ go, int N, int G){
  int i = blockIdx.x*256 + threadIdx.x;
  if (i >= N) return;
  int b = batch[i];
  int prev = (i == 0) ? -1 : batch[i-1];
  for (int g = prev+1; g <= b; ++g) go[g] = i;
  if (i == N-1){
    for (int g = b+1; g <= G; ++g) go[g] = N;
  }
}

// ---------------- fused pool + cond MLP + concat + BN + fc --------------------
__global__ __launch_bounds__(384) void poolfinal_k(
    const float* __restrict__ h, const int* __restrict__ go,
    const float* __restrict__ cond,
    const float* __restrict__ cW1, const float* __restrict__ cb1,
    const float* __restrict__ cg, const float* __restrict__ cbeta,
    const float* __restrict__ cmean, const float* __restrict__ cvar,
    const float* __restrict__ cW2, const float* __restrict__ cb2,
    const float* __restrict__ bn_g, const float* __restrict__ bn_b,
    const float* __restrict__ bn_mean, const float* __restrict__ bn_var,
    const float* __restrict__ fcW, const float* __restrict__ fcb,
    float* __restrict__ out)
{
  __shared__ float ps[4][96];
  __shared__ float pl[96];
  int g = blockIdx.x, t = threadIdx.x;
  int s = t / 96, d = t - s*96;
  {
    float acc = 0.f;
    int nb = go[g], ne = go[g+1];
    for (int n = nb + s; n < ne; n += 4) acc += h[(size_t)n*96 + d];
    ps[s][d] = acc;
  }
  __syncthreads();
  if (t < 96) pl[t] = ps[0][t] + ps[1][t] + ps[2][t] + ps[3][t];
  __syncthreads();

  if (t < 64){
    float cin[7];
    #pragma unroll
    for (int j = 0; j < 7; ++j) cin[j] = cond[g*7+j];
    float c1[5];
    #pragma unroll
    for (int i = 0; i < 5; ++i){
      float a = cb1[i];
      #pragma unroll
      for (int j = 0; j < 7; ++j) a = fmaf(cin[j], cW1[j*5+i], a);
      float sc = cg[i] * rsqrtf(cvar[i] + BN_EPS);
      a = (a - cmean[i])*sc + cbeta[i];
      c1[i] = a > 0.f ? a : 0.f;
    }
    float c2[5];
    #pragma unroll
    for (int i = 0; i < 5; ++i){
      float a = cb2[i];
      #pragma unroll
      for (int j = 0; j < 5; ++j) a = fmaf(c1[j], cW2[j*5+i], a);
      c2[i] = a > 0.f ? a : 0.f;
    }
    float acc = fcb[t];
    #pragma unroll
    for (int j = 0; j < 5; ++j){
      float sc = bn_g[j] * rsqrtf(bn_var[j] + BN_EPS);
      float nb = (c2[j] - bn_mean[j])*sc + bn_b[j];
      acc = fmaf(nb, fcW[j*64 + t], acc);
    }
    for (int j = 5; j < 101; ++j){
      float vj = pl[j-5];
      float sc = bn_g[j] * rsqrtf(bn_var[j] + BN_EPS);
      float nb = (vj - bn_mean[j])*sc + bn_b[j];
      acc = fmaf(nb, fcW[j*64 + t], acc);
    }
    out[g*64 + t] = acc;
  }
}

// ---------------- launch ----------------

extern "C" void kernel_launch(void* const* d_in, const int* in_sizes, int n_in,
                              void* d_out, int out_size, void* d_ws, size_t ws_size,
                              hipStream_t stream)
{
  const float* x         = (const float*)d_in[0];
  const float* cond      = (const float*)d_in[1];
  const int*   ei        = (const int*)  d_in[2];
  const int*   batch     = (const int*)  d_in[3];
  const float* conv_W1   = (const float*)d_in[4];
  const float* conv_b1   = (const float*)d_in[5];
  const float* conv_g    = (const float*)d_in[6];
  const float* conv_beta = (const float*)d_in[7];
  const float* conv_mean = (const float*)d_in[8];
  const float* conv_var  = (const float*)d_in[9];
  const float* conv_W2   = (const float*)d_in[10];
  const float* conv_b2   = (const float*)d_in[11];
  const float* cW1       = (const float*)d_in[12];
  const float* cb1       = (const float*)d_in[13];
  const float* cg        = (const float*)d_in[14];
  const float* cbeta     = (const float*)d_in[15];
  const float* cmean     = (const float*)d_in[16];
  const float* cvar      = (const float*)d_in[17];
  const float* cW2       = (const float*)d_in[18];
  const float* cb2       = (const float*)d_in[19];
  const float* bn_g      = (const float*)d_in[20];
  const float* bn_b      = (const float*)d_in[21];
  const float* bn_mean   = (const float*)d_in[22];
  const float* bn_var    = (const float*)d_in[23];
  const float* fc_W      = (const float*)d_in[24];
  const float* fc_b      = (const float*)d_in[25];

  const int D = 96;
  int N = in_sizes[0] / D;
  int G = in_sizes[1] / 7;
  int E = in_sizes[2] / 2;
  const int* src = ei;
  const int* dst = ei + E;

  char* p = (char*)d_ws;
  auto carve = [&](size_t bytes)->void*{
    void* r = (void*)p; p += (bytes + 255) & ~(size_t)255; return r;
  };
  int*   off     = (int*)  carve((size_t)(N+1)*4);
  int*   bsum    = (int*)  carve(256*4);
  int*   bcnt    = (int*)  carve(512*4);
  int*   bkt_off = (int*)  carve(513*4);
  int*   gcur    = (int*)  carve(512*4);
  int2*  ebuf    = (int2*) carve((size_t)E*8);
  int*   srcs    = (int*)  carve((size_t)E*4);
  int*   go      = (int*)  carve((size_t)(G+1)*4);
  short* Wpk     = (short*)carve(6*18432*2);
  float* hA      = (float*)carve((size_t)N*D*4);
  float* hB      = (float*)carve((size_t)N*D*4);

  int gN = (N+255)/256, gEB = (E+EB-1)/EB;

  hipMemsetAsync(off,  0, (size_t)(N+1)*4, stream);
  hipMemsetAsync(bcnt, 0, 512*4, stream);
  wprep_k<<<6, 256, 0, stream>>>(conv_W1, conv_W2, Wpk);
  hist2_k<<<gEB, 256, 0, stream>>>(dst, off, bcnt, E);
  scan1_k<<<gN, 256, 0, stream>>>(off, bsum, N);
  scan2_k<<<1,  256, 0, stream>>>(bsum, gN);
  scan3_k<<<gN, 256, 0, stream>>>(off, bsum, N, E);
  bscan_k<<<1,  512, 0, stream>>>(bcnt, bkt_off, gcur, E);
  bpart_k<<<gEB, 256, 0, stream>>>(src, dst, gcur, ebuf, E);
  bscat_k<<<512, 256, 0, stream>>>(ebuf, bkt_off, off, srcs, N);
  bounds_k<<<gN, 256, 0, stream>>>(batch, go, N, G);

  const float* hin = x;
  int nblk = (N+63)/64;
  for (int l = 0; l < 3; ++l){
    agg_k<<<(N+7)/8, 256, 0, stream>>>(hin, hB, off, srcs, N);
    const short* Whi1 = Wpk + (size_t)(2*l)  *18432;
    const short* Wlo1 = Whi1 + 9216;
    const short* Whi2 = Wpk + (size_t)(2*l+1)*18432;
    const short* Wlo2 = Whi2 + 9216;
    mlp_mfma_k<<<nblk, 256, 0, stream>>>(hB, hA, Whi1, Wlo1, Whi2, Wlo2,
        conv_b1 + l*D, conv_g + l*D, conv_beta + l*D, conv_mean + l*D,
        conv_var + l*D, conv_b2 + l*D, N);
    hin = hA;
  }

  poolfinal_k<<<G, 384, 0, stream>>>(hA, go, cond,
                                     cW1, cb1, cg, cbeta, cmean, cvar,
                                     cW2, cb2, bn_g, bn_b, bn_mean, bn_var,
                                     fc_W, fc_b, (float*)d_out);
}

// Round 13
// 393.245 us; speedup vs baseline: 1.4212x; 1.0704x over previous
//
#include <hip/hip_runtime.h>
#include <hip/hip_fp16.h>

#define BN_EPS 1e-5f

__device__ __forceinline__ float lrelu(float x){ return x > 0.f ? x : 0.2f*x; }

struct F3 { float x, y, z; };   // 12B -> global_load_dwordx3
struct U3 { unsigned x, y, z; };// 12B (6 fp16)

typedef __attribute__((ext_vector_type(8))) short short8v;  // 8 bf16 (4 VGPR)
typedef __attribute__((ext_vector_type(4))) float f32x4;

__device__ __forceinline__ void addh2(unsigned u, float& a, float& b){
  __half2 h = *(__half2*)&u;
  a += __low2float(h); b += __high2float(h);
}

#define EB 4096          // edges per partition block

// ---------------- merged histograms: node degree + bucket counts --------------
__global__ __launch_bounds__(256) void hist2_k(const int* __restrict__ dst,
                                               int* __restrict__ deg,
                                               int* __restrict__ bcnt, int E){
  __shared__ int bh[512];
  int t = threadIdx.x;
  bh[t] = 0; bh[t+256] = 0;
  __syncthreads();
  int e0 = blockIdx.x*EB;
  for (int i = 0; i < EB/256; ++i){
    int e = e0 + i*256 + t;
    if (e < E){
      int d = dst[e];
      atomicAdd(&deg[d], 1);
      atomicAdd(&bh[d >> 7], 1);
    }
  }
  __syncthreads();
  if (bh[t])     atomicAdd(&bcnt[t],     bh[t]);
  if (bh[t+256]) atomicAdd(&bcnt[t+256], bh[t+256]);
}

// ---------------- CSR offset scan ----------------
__global__ __launch_bounds__(256) void scan1_k(int* __restrict__ degoff,
                                               int* __restrict__ bsum, int N){
  __shared__ int s[256];
  int t = threadIdx.x, i = blockIdx.x*256 + t;
  int v = (i < N) ? degoff[i] : 0;
  s[t] = v; __syncthreads();
  int x = v;
  for (int d = 1; d < 256; d <<= 1){
    int y = (t >= d) ? s[t-d] : 0;
    __syncthreads();
    x += y; s[t] = x;
    __syncthreads();
  }
  if (i < N) degoff[i] = x - v;
  if (t == 255) bsum[blockIdx.x] = x;
}

__global__ __launch_bounds__(256) void scan2_k(int* __restrict__ bsum, int nb){
  __shared__ int s[256];
  int t = threadIdx.x;
  int v = (t < nb) ? bsum[t] : 0;
  s[t] = v; __syncthreads();
  int x = v;
  for (int d = 1; d < 256; d <<= 1){
    int y = (t >= d) ? s[t-d] : 0;
    __syncthreads();
    x += y; s[t] = x;
    __syncthreads();
  }
  if (t < nb) bsum[t] = x - v;
}

__global__ __launch_bounds__(256) void scan3_k(int* __restrict__ off,
                                               const int* __restrict__ bsum,
                                               int N, int E){
  int i = blockIdx.x*256 + threadIdx.x;
  if (i < N) off[i] += bsum[blockIdx.x];
  if (i == 0) off[N] = E;
}

// ---------------- bucketed edge partition ----------------
__global__ __launch_bounds__(512) void bscan_k(const int* __restrict__ bcnt,
                                               int* __restrict__ bkt_off,
                                               int* __restrict__ gcur, int E){
  __shared__ int s[512];
  int t = threadIdx.x;
  int v = bcnt[t];
  s[t] = v; __syncthreads();
  int x = v;
  for (int d = 1; d < 512; d <<= 1){
    int y = (t >= d) ? s[t-d] : 0;
    __syncthreads();
    x += y; s[t] = x;
    __syncthreads();
  }
  bkt_off[t] = x - v;
  gcur[t]    = x - v;
  if (t == 511) bkt_off[512] = E;
}

__global__ __launch_bounds__(256) void bpart_k(const int* __restrict__ src,
                                               const int* __restrict__ dst,
                                               int* __restrict__ gcur,
                                               int2* __restrict__ ebuf, int E){
  __shared__ int bh[512];
  __shared__ int base[512];
  int t = threadIdx.x;
  bh[t] = 0; bh[t+256] = 0;
  __syncthreads();
  int e0 = blockIdx.x*EB;
  for (int i = 0; i < EB/256; ++i){
    int e = e0 + i*256 + t;
    if (e < E) atomicAdd(&bh[dst[e] >> 7], 1);
  }
  __syncthreads();
  #pragma unroll
  for (int h = 0; h < 2; ++h){
    int b = t + h*256;
    base[b] = bh[b] ? atomicAdd(&gcur[b], bh[b]) : 0;
  }
  __syncthreads();
  for (int i = 0; i < EB/256; ++i){
    int e = e0 + i*256 + t;
    if (e < E){
      int s = src[e], d = dst[e];
      int p = atomicAdd(&base[d >> 7], 1);
      ebuf[p] = make_int2(s, d);
    }
  }
}

__global__ __launch_bounds__(256) void bscat_k(const int2* __restrict__ ebuf,
                                               const int* __restrict__ bkt_off,
                                               const int* __restrict__ off,
                                               int* __restrict__ srcs, int N){
  __shared__ int lcur[128];
  int b = blockIdx.x, t = threadIdx.x;
  int node_lo = b << 7;
  if (t < 128){
    int n = node_lo + t;
    lcur[t] = (n < N) ? off[n] : 0;
  }
  __syncthreads();
  int eb = bkt_off[b], ee = bkt_off[b+1];
  for (int e = eb + t; e < ee; e += 256){
    int2 sd = ebuf[e];
    int p = atomicAdd(&lcur[sd.y - node_lo], 1);
    srcs[p] = sd.x;
  }
}

// ---------------- x -> fp16 gather table ----------------
__global__ __launch_bounds__(256) void xcvt_k(const float* __restrict__ x,
                                              __half* __restrict__ hc, int total){
  for (int i = blockIdx.x*256 + threadIdx.x; i < total; i += gridDim.x*256)
    hc[i] = __float2half(x[i]);
}

// ---------------- GIN aggregation: fp16 gather, 16 lanes/node, 4-deep ---------
// lane owns feats 6ln..6ln+5 (one dwordx3 = 6 fp16 per edge); f32 accumulate.
__global__ __launch_bounds__(256) void agg_k(const __half* __restrict__ hc,
                                             float* __restrict__ hout,
                                             const int* __restrict__ off,
                                             const int* __restrict__ srcs, int N){
  int node = blockIdx.x*16 + (threadIdx.x >> 4);
  int ln = threadIdx.x & 15;
  if (node >= N) return;
  const char* hb = (const char*)hc;
  size_t lnoff = (size_t)ln*12;

  float a0,a1,a2,a3,a4,a5;
  {
    U3 q = *(const U3*)(hb + (size_t)node*192 + lnoff);
    a0=a1=a2=a3=a4=a5=0.f;
    addh2(q.x, a0, a1); addh2(q.y, a2, a3); addh2(q.z, a4, a5);
  }
  float b0=0,b1=0,b2=0,b3=0,b4=0,b5=0;
  float c0=0,c1=0,c2=0,c3=0,c4=0,c5=0;
  float d0=0,d1=0,d2=0,d3=0,d4=0,d5=0;

  int jb = off[node], je = off[node+1];
  int j = jb;
  for (; j+3 < je; j += 4){
    int s0 = srcs[j], s1 = srcs[j+1], s2 = srcs[j+2], s3 = srcs[j+3];
    U3 q0 = *(const U3*)(hb + (size_t)s0*192 + lnoff);
    U3 q1 = *(const U3*)(hb + (size_t)s1*192 + lnoff);
    U3 q2 = *(const U3*)(hb + (size_t)s2*192 + lnoff);
    U3 q3 = *(const U3*)(hb + (size_t)s3*192 + lnoff);
    addh2(q0.x, a0, a1); addh2(q0.y, a2, a3); addh2(q0.z, a4, a5);
    addh2(q1.x, b0, b1); addh2(q1.y, b2, b3); addh2(q1.z, b4, b5);
    addh2(q2.x, c0, c1); addh2(q2.y, c2, c3); addh2(q2.z, c4, c5);
    addh2(q3.x, d0, d1); addh2(q3.y, d2, d3); addh2(q3.z, d4, d5);
  }
  for (; j < je; ++j){
    U3 q = *(const U3*)(hb + (size_t)srcs[j]*192 + lnoff);
    addh2(q.x, a0, a1); addh2(q.y, a2, a3); addh2(q.z, a4, a5);
  }
  a0 += b0+c0+d0; a1 += b1+c1+d1; a2 += b2+c2+d2;
  a3 += b3+c3+d3; a4 += b4+c4+d4; a5 += b5+c5+d5;

  float* o = hout + (size_t)node*96 + ln*6;
  F3 w0 = {a0, a1, a2}, w1 = {a3, a4, a5};
  *(F3*)(o)   = w0;
  *(F3*)(o+3) = w1;
}

// ---------------- W -> MFMA fragment pre-pack (split-bf16 hi/lo) --------------
__global__ __launch_bounds__(256) void wprep_k(const float* __restrict__ W1b,
                                               const float* __restrict__ W2b,
                                               short* __restrict__ Wpk){
  int mat = blockIdx.x;                 // 0..5 : {l0W1,l0W2,l1W1,l1W2,l2W1,l2W2}
  int layer = mat >> 1, which = mat & 1;
  const float* src = (which ? W2b : W1b) + (size_t)layer*9216;
  short* hi = Wpk + (size_t)mat*18432;
  short* lo = hi + 9216;
  for (int i = threadIdx.x; i < 9216; i += 256){
    int j = i & 7, lane = (i >> 3) & 63, grp = i >> 9;
    int kb = grp / 6, nt = grp - 6*kb;
    int k = 32*kb + 8*(lane>>4) + j;
    int n = 16*nt + (lane&15);
    float v = src[k*96 + n];
    unsigned b = __float_as_uint(v);
    unsigned short hb = (unsigned short)(b >> 16);
    float hf = __uint_as_float((unsigned)hb << 16);
    float lof = v - hf;
    hi[i] = (short)hb;
    lo[i] = (short)(__float_as_uint(lof) >> 16);
  }
}

// ---------------- MFMA MLP: split-bf16, 64-node tile, 4 waves -----------------
// Dual store: f32 hout (next agg-input f32 path / pool) + fp16 hcout (gather).
__global__ __launch_bounds__(256) void mlp_mfma_k(
    const float* __restrict__ hin, float* __restrict__ hout,
    __half* __restrict__ hcout,
    const short* __restrict__ Whi1, const short* __restrict__ Wlo1,
    const short* __restrict__ Whi2, const short* __restrict__ Wlo2,
    const float* __restrict__ b1, const float* __restrict__ g,
    const float* __restrict__ beta, const float* __restrict__ mean,
    const float* __restrict__ var, const float* __restrict__ b2, int N)
{
  __shared__ float hT[64*97];          // 24.8 KB
  int t = threadIdx.x;
  int nbase = blockIdx.x * 64;
  int lim = (N - nbase) * 96;
  const float* hbase = hin + (size_t)nbase*96;

  #pragma unroll
  for (int i = 0; i < 24; ++i){        // coalesced stage-in
    int tid = t + 256*i;
    float v = (tid < lim) ? hbase[tid] : 0.f;
    int n = tid / 96, k = tid - n*96;
    hT[n*97 + k] = v;
  }
  __syncthreads();

  int l = t & 63, w = t >> 6;
  int kgrp = l >> 4;
  int arow = 16*w + (l & 15);          // A row (M) for this lane
  int col  = l & 15;                   // B/C col within nt tile

  // ---- A fragments (hi/lo) for GEMM1 ----
  short8v ah[3], al[3];
  #pragma unroll
  for (int kb = 0; kb < 3; ++kb){
    const float* ap = &hT[arow*97 + 32*kb + 8*kgrp];
    #pragma unroll
    for (int j = 0; j < 8; ++j){
      float v = ap[j];
      unsigned bits = __float_as_uint(v);
      unsigned short hb = (unsigned short)(bits >> 16);
      float hf = __uint_as_float((unsigned)hb << 16);
      unsigned short lb = (unsigned short)(__float_as_uint(v - hf) >> 16);
      ah[kb][j] = (short)hb;
      al[kb][j] = (short)lb;
    }
  }

  // ---- GEMM1 + BN + lrelu (results in regs) ----
  float mid[6][4];
  {
    const short8v* BH = (const short8v*)Whi1;
    const short8v* BL = (const short8v*)Wlo1;
    #pragma unroll
    for (int nt = 0; nt < 6; ++nt){
      int d = 16*nt + col;
      float bv = b1[d];
      f32x4 acc; acc[0]=bv; acc[1]=bv; acc[2]=bv; acc[3]=bv;
      #pragma unroll
      for (int kb = 0; kb < 3; ++kb){
        short8v bh = BH[(kb*6 + nt)*64 + l];
        short8v bl = BL[(kb*6 + nt)*64 + l];
        acc = __builtin_amdgcn_mfma_f32_16x16x32_bf16(ah[kb], bh, acc, 0,0,0);
        acc = __builtin_amdgcn_mfma_f32_16x16x32_bf16(ah[kb], bl, acc, 0,0,0);
        acc = __builtin_amdgcn_mfma_f32_16x16x32_bf16(al[kb], bh, acc, 0,0,0);
      }
      float s  = g[d] * rsqrtf(var[d] + BN_EPS);
      float mu = mean[d], bt = beta[d];
      #pragma unroll
      for (int r = 0; r < 4; ++r)
        mid[nt][r] = (lrelu(acc[r]) - mu)*s + bt;
    }
  }
  __syncthreads();                     // all hT reads (A frags) done

  // ---- mid -> hT in C layout: row = 16w + 4*kgrp + r, col = 16nt+col ----
  #pragma unroll
  for (int nt = 0; nt < 6; ++nt)
    #pragma unroll
    for (int r = 0; r < 4; ++r)
      hT[(16*w + 4*kgrp + r)*97 + 16*nt + col] = mid[nt][r];
  __syncthreads();

  // ---- A fragments for GEMM2 ----
  #pragma unroll
  for (int kb = 0; kb < 3; ++kb){
    const float* ap = &hT[arow*97 + 32*kb + 8*kgrp];
    #pragma unroll
    for (int j = 0; j < 8; ++j){
      float v = ap[j];
      unsigned bits = __float_as_uint(v);
      unsigned short hb = (unsigned short)(bits >> 16);
      float hf = __uint_as_float((unsigned)hb << 16);
      unsigned short lb = (unsigned short)(__float_as_uint(v - hf) >> 16);
      ah[kb][j] = (short)hb;
      al[kb][j] = (short)lb;
    }
  }

  // ---- GEMM2 + lrelu ----
  float outr[6][4];
  {
    const short8v* BH = (const short8v*)Whi2;
    const short8v* BL = (const short8v*)Wlo2;
    #pragma unroll
    for (int nt = 0; nt < 6; ++nt){
      float bv = b2[16*nt + col];
      f32x4 acc; acc[0]=bv; acc[1]=bv; acc[2]=bv; acc[3]=bv;
      #pragma unroll
      for (int kb = 0; kb < 3; ++kb){
        short8v bh = BH[(kb*6 + nt)*64 + l];
        short8v bl = BL[(kb*6 + nt)*64 + l];
        acc = __builtin_amdgcn_mfma_f32_16x16x32_bf16(ah[kb], bh, acc, 0,0,0);
        acc = __builtin_amdgcn_mfma_f32_16x16x32_bf16(ah[kb], bl, acc, 0,0,0);
        acc = __builtin_amdgcn_mfma_f32_16x16x32_bf16(al[kb], bh, acc, 0,0,0);
      }
      #pragma unroll
      for (int r = 0; r < 4; ++r) outr[nt][r] = lrelu(acc[r]);
    }
  }
  __syncthreads();                     // all hT reads done before overwrite

  #pragma unroll
  for (int nt = 0; nt < 6; ++nt)
    #pragma unroll
    for (int r = 0; r < 4; ++r)
      hT[(16*w + 4*kgrp + r)*97 + 16*nt + col] = outr[nt][r];
  __syncthreads();

  float*  obase = hout  + (size_t)nbase*96;
  __half* cbase = hcout + (size_t)nbase*96;
  #pragma unroll
  for (int i = 0; i < 24; ++i){        // coalesced dual store (f32 + fp16)
    int tid = t + 256*i;
    int n = tid / 96, k = tid - n*96;
    if (tid < lim){
      float v = hT[n*97 + k];
      obase[tid] = v;
      cbase[tid] = __float2half(v);
    }
  }
}

// ---------------- pooling bounds over sorted batch ----------------
__global__ __launch_bounds__(256) void bounds_k(const int* __restrict__ batch,
                                                int* __restrict__ go, int N, int G){
  int i = blockIdx.x*256 + threadIdx.x;
  if (i >= N) return;
  int b = batch[i];
  int prev = (i == 0) ? -1 : batch[i-1];
  for (int g = prev+1; g <= b; ++g) go[g] = i;
  if (i == N-1){
    for (int g = b+1; g <= G; ++g) go[g] = N;
  }
}

// ---------------- fused pool + cond MLP + concat + BN + fc --------------------
__global__ __launch_bounds__(384) void poolfinal_k(
    const float* __restrict__ h, const int* __restrict__ go,
    const float* __restrict__ cond,
    const float* __restrict__ cW1, const float* __restrict__ cb1,
    const float* __restrict__ cg, const float* __restrict__ cbeta,
    const float* __restrict__ cmean, const float* __restrict__ cvar,
    const float* __restrict__ cW2, const float* __restrict__ cb2,
    const float* __restrict__ bn_g, const float* __restrict__ bn_b,
    const float* __restrict__ bn_mean, const float* __restrict__ bn_var,
    const float* __restrict__ fcW, const float* __restrict__ fcb,
    float* __restrict__ out)
{
  __shared__ float ps[4][96];
  __shared__ float pl[96];
  int g = blockIdx.x, t = threadIdx.x;
  int s = t / 96, d = t - s*96;
  {
    float acc = 0.f;
    int nb = go[g], ne = go[g+1];
    for (int n = nb + s; n < ne; n += 4) acc += h[(size_t)n*96 + d];
    ps[s][d] = acc;
  }
  __syncthreads();
  if (t < 96) pl[t] = ps[0][t] + ps[1][t] + ps[2][t] + ps[3][t];
  __syncthreads();

  if (t < 64){
    float cin[7];
    #pragma unroll
    for (int j = 0; j < 7; ++j) cin[j] = cond[g*7+j];
    float c1[5];
    #pragma unroll
    for (int i = 0; i < 5; ++i){
      float a = cb1[i];
      #pragma unroll
      for (int j = 0; j < 7; ++j) a = fmaf(cin[j], cW1[j*5+i], a);
      float sc = cg[i] * rsqrtf(cvar[i] + BN_EPS);
      a = (a - cmean[i])*sc + cbeta[i];
      c1[i] = a > 0.f ? a : 0.f;
    }
    float c2[5];
    #pragma unroll
    for (int i = 0; i < 5; ++i){
      float a = cb2[i];
      #pragma unroll
      for (int j = 0; j < 5; ++j) a = fmaf(c1[j], cW2[j*5+i], a);
      c2[i] = a > 0.f ? a : 0.f;
    }
    float acc = fcb[t];
    #pragma unroll
    for (int j = 0; j < 5; ++j){
      float sc = bn_g[j] * rsqrtf(bn_var[j] + BN_EPS);
      float nb = (c2[j] - bn_mean[j])*sc + bn_b[j];
      acc = fmaf(nb, fcW[j*64 + t], acc);
    }
    for (int j = 5; j < 101; ++j){
      float vj = pl[j-5];
      float sc = bn_g[j] * rsqrtf(bn_var[j] + BN_EPS);
      float nb = (vj - bn_mean[j])*sc + bn_b[j];
      acc = fmaf(nb, fcW[j*64 + t], acc);
    }
    out[g*64 + t] = acc;
  }
}

// ---------------- launch ----------------

extern "C" void kernel_launch(void* const* d_in, const int* in_sizes, int n_in,
                              void* d_out, int out_size, void* d_ws, size_t ws_size,
                              hipStream_t stream)
{
  const float* x         = (const float*)d_in[0];
  const float* cond      = (const float*)d_in[1];
  const int*   ei        = (const int*)  d_in[2];
  const int*   batch     = (const int*)  d_in[3];
  const float* conv_W1   = (const float*)d_in[4];
  const float* conv_b1   = (const float*)d_in[5];
  const float* conv_g    = (const float*)d_in[6];
  const float* conv_beta = (const float*)d_in[7];
  const float* conv_mean = (const float*)d_in[8];
  const float* conv_var  = (const float*)d_in[9];
  const float* conv_W2   = (const float*)d_in[10];
  const float* conv_b2   = (const float*)d_in[11];
  const float* cW1       = (const float*)d_in[12];
  const float* cb1       = (const float*)d_in[13];
  const float* cg        = (const float*)d_in[14];
  const float* cbeta     = (const float*)d_in[15];
  const float* cmean     = (const float*)d_in[16];
  const float* cvar      = (const float*)d_in[17];
  const float* cW2       = (const float*)d_in[18];
  const float* cb2       = (const float*)d_in[19];
  const float* bn_g      = (const float*)d_in[20];
  const float* bn_b      = (const float*)d_in[21];
  const float* bn_mean   = (const float*)d_in[22];
  const float* bn_var    = (const float*)d_in[23];
  const float* fc_W      = (const float*)d_in[24];
  const float* fc_b      = (const float*)d_in[25];

  const int D = 96;
  int N = in_sizes[0] / D;
  int G = in_sizes[1] / 7;
  int E = in_sizes[2] / 2;
  const int* src = ei;
  const int* dst = ei + E;

  char* p = (char*)d_ws;
  auto carve = [&](size_t bytes)->void*{
    void* r = (void*)p; p += (bytes + 255) & ~(size_t)255; return r;
  };
  int*    off     = (int*)   carve((size_t)(N+1)*4);
  int*    bsum    = (int*)   carve(256*4);
  int*    bcnt    = (int*)   carve(512*4);
  int*    bkt_off = (int*)   carve(513*4);
  int*    gcur    = (int*)   carve(512*4);
  int2*   ebuf    = (int2*)  carve((size_t)E*8);
  int*    srcs    = (int*)   carve((size_t)E*4);
  int*    go      = (int*)   carve((size_t)(G+1)*4);
  short*  Wpk     = (short*) carve(6*18432*2);
  __half* hC      = (__half*)carve((size_t)N*D*2);
  float*  hA      = (float*) carve((size_t)N*D*4);
  float*  hB      = (float*) carve((size_t)N*D*4);

  int gN = (N+255)/256, gEB = (E+EB-1)/EB;

  hipMemsetAsync(off,  0, (size_t)(N+1)*4, stream);
  hipMemsetAsync(bcnt, 0, 512*4, stream);
  xcvt_k <<<2048, 256, 0, stream>>>(x, hC, N*D);
  wprep_k<<<6, 256, 0, stream>>>(conv_W1, conv_W2, Wpk);
  hist2_k<<<gEB, 256, 0, stream>>>(dst, off, bcnt, E);
  scan1_k<<<gN, 256, 0, stream>>>(off, bsum, N);
  scan2_k<<<1,  256, 0, stream>>>(bsum, gN);
  scan3_k<<<gN, 256, 0, stream>>>(off, bsum, N, E);
  bscan_k<<<1,  512, 0, stream>>>(bcnt, bkt_off, gcur, E);
  bpart_k<<<gEB, 256, 0, stream>>>(src, dst, gcur, ebuf, E);
  bscat_k<<<512, 256, 0, stream>>>(ebuf, bkt_off, off, srcs, N);
  bounds_k<<<gN, 256, 0, stream>>>(batch, go, N, G);

  const float* hin = x;
  int nblk = (N+63)/64;
  for (int l = 0; l < 3; ++l){
    agg_k<<<(N+15)/16, 256, 0, stream>>>(hC, hB, off, srcs, N);
    const short* Whi1 = Wpk + (size_t)(2*l)  *18432;
    const short* Wlo1 = Whi1 + 9216;
    const short* Whi2 = Wpk + (size_t)(2*l+1)*18432;
    const short* Wlo2 = Whi2 + 9216;
    mlp_mfma_k<<<nblk, 256, 0, stream>>>(hB, hA, hC, Whi1, Wlo1, Whi2, Wlo2,
        conv_b1 + l*D, conv_g + l*D, conv_beta + l*D, conv_mean + l*D,
        conv_var + l*D, conv_b2 + l*D, N);
    hin = hA;
  }

  poolfinal_k<<<G, 384, 0, stream>>>(hA, go, cond,
                                     cW1, cb1, cg, cbeta, cmean, cvar,
                                     cW2, cb2, bn_g, bn_b, bn_mean, bn_var,
                                     fc_W, fc_b, (float*)d_out);
}